// Round 5
// baseline (73.335 us; speedup 1.0000x reference)
//
#include <hip/hip_runtime.h>
#include <hip/hip_bf16.h>

// GraphConvolution: out[b] = adj[b] @ (feat[b] @ W) + bias
// B=32, N=1024, IN=256, OUT=256. fp32 in/out, bf16 MFMA internally.
//
// ws: [0,128KB)  Wt = W^T bf16, k-subtiled: [k>>3][n=256][8]
//     [128KB..)  St = support bf16, k-subtiled per batch:
//                 [b][m>>3][n=256][8]   (m is gemm2's reduction dim)
//
// Round-5 structure: BARRIER-FREE all-register waveGEMM.
//   Each wave owns a 32(m) x 128(n) output tile. Per k-step (BK=32):
//     A: 4x global_load_dwordx4, fp32, natural MFMA layout (16 rows x 16B at
//        4KB stride -> dense 128B lines with sibling instrs), cvt->bf16 in reg.
//     B: 8x global_load_dwordx4 from k-subtiled St/Wt (256B-contiguous per
//        16-lane group), L2-resident (St[b]=512KB, XCD-swizzled; Wt=128KB).
//     16x mfma_16x16x32_bf16.
//   Depth-2 named register sets (a0/b0, a1/b1); no LDS, no __syncthreads,
//   no convoy: every wave's vmcnt waits are private. 8 waves/CU x ~8KB in
//   flight = 64KB/CU >> 10KB Little's-law demand at 900cyc HBM latency.

typedef __attribute__((__ext_vector_type__(4))) float  f32x4;
typedef __attribute__((__ext_vector_type__(8))) __bf16 bf16x8;
typedef __attribute__((__ext_vector_type__(4))) __bf16 bf16x4;

#define BK 32

// ---- weight transpose: w[k][n] fp32 -> Wt k-subtiled [k>>3][n][8] bf16 -----
__global__ __launch_bounds__(256) void k_wt(const float* __restrict__ w,
                                            __bf16* __restrict__ Wt) {
  __shared__ __bf16 T[64][65];
  const int bi = blockIdx.x >> 2;  // k tile
  const int bj = blockIdx.x & 3;   // n tile
  const int t  = threadIdx.x;
  const int r  = t >> 2;
  const int q  = t & 3;
  const float* src = w + (size_t)(bi * 64 + r) * 256 + bj * 64 + q * 16;
#pragma unroll
  for (int u = 0; u < 4; ++u) {
    f32x4 v = *(const f32x4*)(src + u * 4);
    T[r][q * 16 + u * 4 + 0] = (__bf16)v[0];
    T[r][q * 16 + u * 4 + 1] = (__bf16)v[1];
    T[r][q * 16 + u * 4 + 2] = (__bf16)v[2];
    T[r][q * 16 + u * 4 + 3] = (__bf16)v[3];
  }
  __syncthreads();
  bf16x8 h0, h1;
#pragma unroll
  for (int u = 0; u < 8; ++u) {
    h0[u] = T[q * 16 + u][r];      // k = bi*64+q*16+u,   n = bj*64+r
    h1[u] = T[q * 16 + 8 + u][r];  // k = bi*64+q*16+8+u
  }
  // element (n,k) -> [(k>>3)*256 + n]*8 + (k&7)
  __bf16* d0 = Wt + ((size_t)(bi * 8 + q * 2) * 256 + (bj * 64 + r)) * 8;
  *(bf16x8*)d0          = h0;
  *(bf16x8*)(d0 + 2048) = h1;
}

// ---- barrier-free waveGEMM -------------------------------------------------
// block = 256 thr = 4 waves; wave w: m-sub = w>>1 (2 x 32 rows), n-half = w&1.
// Block tile 64(m) x 256(n). Grid = 512 blocks (32 batches x 16 m-tiles).
// EPI_ST=true : epilogue -> St k-subtiled bf16 (gemm1: feat @ W)
// EPI_ST=false: epilogue -> Out fp32 + bias, XCD swizzle (gemm2)
template <int KTOT, int LDA, bool EPI_ST>
__global__ __launch_bounds__(256, 2) void k_gemm(
    const float* __restrict__ Aall, const __bf16* __restrict__ Bg_all,
    const float* __restrict__ bias, float* __restrict__ Out,
    __bf16* __restrict__ St) {
  const int tid  = threadIdx.x;
  const int lane = tid & 63;
  const int w    = tid >> 6;
  const int l16  = lane & 15;
  const int g    = lane >> 4;      // k-chunk 0..3 (8 k each)

  int b, mblk;
  const float*  Ablk;
  const __bf16* Bblk;
  if constexpr (EPI_ST) {
    const int bx = blockIdx.x;     // 512 blocks: rows globally contiguous
    b    = bx >> 4;
    mblk = bx & 15;
    Ablk = Aall + (size_t)bx * 64 * LDA;
    Bblk = Bg_all;                 // Wt (128 KB, L2-resident everywhere)
  } else {
    const int h  = blockIdx.x;     // 512 % 8 == 0: bijective XCD swizzle
    const int lg = (h & 7) * 64 + (h >> 3);  // XCD x owns batches 4x..4x+3
    b    = lg >> 4;
    mblk = lg & 15;
    Ablk = Aall + (size_t)b * 1024 * 1024 + (size_t)mblk * 64 * LDA;
    Bblk = Bg_all + (size_t)b * 262144;      // St[b], k-subtiled, L2-hot
  }

  const int wm = (w >> 1) * 32;    // wave m offset in block tile
  const int nb = (w & 1) * 128;    // wave n offset

  // A lane pointers: rows wm+l16 and wm+l16+16, k-chunk g*8
  const float* arow0 = Ablk + (size_t)(wm + l16) * LDA + g * 8;
  const float* arow1 = arow0 + (size_t)16 * LDA;
  // B lane pointer: element (g*2048) + (nb+l16)*8 ; frag n at +n*128 elements
  const __bf16* bl = Bblk + (size_t)g * 2048 + (size_t)(nb + l16) * 8;

  f32x4  a0[4], a1[4];
  bf16x8 b0[8], b1[8];

  auto issueA = [&](f32x4* a, int k0) {
    a[0] = *(const f32x4*)(arow0 + k0);
    a[1] = *(const f32x4*)(arow0 + k0 + 4);
    a[2] = *(const f32x4*)(arow1 + k0);
    a[3] = *(const f32x4*)(arow1 + k0 + 4);
  };
  auto issueB = [&](bf16x8* bb, int k0) {
    const __bf16* p = bl + (size_t)(k0 >> 3) * 2048;
#pragma unroll
    for (int n = 0; n < 8; ++n) bb[n] = *(const bf16x8*)(p + n * 128);
  };

  f32x4 acc[2][8];
#pragma unroll
  for (int m = 0; m < 2; ++m)
#pragma unroll
    for (int n = 0; n < 8; ++n) acc[m][n] = (f32x4){0.f, 0.f, 0.f, 0.f};

  auto step = [&](const f32x4* a, const bf16x8* bb) {
    bf16x8 af0 = {(__bf16)a[0][0], (__bf16)a[0][1], (__bf16)a[0][2], (__bf16)a[0][3],
                  (__bf16)a[1][0], (__bf16)a[1][1], (__bf16)a[1][2], (__bf16)a[1][3]};
    bf16x8 af1 = {(__bf16)a[2][0], (__bf16)a[2][1], (__bf16)a[2][2], (__bf16)a[2][3],
                  (__bf16)a[3][0], (__bf16)a[3][1], (__bf16)a[3][2], (__bf16)a[3][3]};
#pragma unroll
    for (int n = 0; n < 8; ++n) {
      acc[0][n] = __builtin_amdgcn_mfma_f32_16x16x32_bf16(af0, bb[n], acc[0][n], 0, 0, 0);
      acc[1][n] = __builtin_amdgcn_mfma_f32_16x16x32_bf16(af1, bb[n], acc[1][n], 0, 0, 0);
    }
  };

  constexpr int NT = KTOT / BK;    // 8 (gemm1) or 32 (gemm2), even
  issueA(a0, 0);   issueB(b0, 0);
  issueA(a1, BK);  issueB(b1, BK);
  for (int t = 0; t < NT - 2; t += 2) {
    step(a0, b0);                  // consume tile t (waits only its own regs)
    issueA(a0, (t + 2) * BK);      // reissue set0 for t+2: ~1.5 steps ahead
    issueB(b0, (t + 2) * BK);
    step(a1, b1);                  // consume tile t+1
    issueA(a1, (t + 3) * BK);
    issueB(b1, (t + 3) * BK);
  }
  step(a0, b0);                    // tile NT-2
  step(a1, b1);                    // tile NT-1

  // --- epilogue. C/D frag: col = lane&15, row = (lane>>4)*4 + reg ---
  const int rg = g * 4;
  if constexpr (EPI_ST) {
    __bf16* Stb = St + (size_t)b * 262144;
    const int gm0 = mblk * 64 + wm;
#pragma unroll
    for (int n = 0; n < 8; ++n) {
      const int col = nb + n * 16 + l16;
#pragma unroll
      for (int m = 0; m < 2; ++m) {
        const int gm = gm0 + m * 16 + rg;   // multiple of 4; gm&7 in {0,4}
        __bf16* dst = Stb + (size_t)(gm >> 3) * 2048 + (size_t)col * 8 + (gm & 7);
        bf16x4 hh = {(__bf16)acc[m][n][0], (__bf16)acc[m][n][1],
                     (__bf16)acc[m][n][2], (__bf16)acc[m][n][3]};
        *(bf16x4*)dst = hh;
      }
    }
  } else {
    float* ob = Out + ((size_t)b * 1024 + (size_t)mblk * 64 + wm) * 256;
#pragma unroll
    for (int n = 0; n < 8; ++n) {
      const int col = nb + n * 16 + l16;
      const float bvs = bias[col];
#pragma unroll
      for (int m = 0; m < 2; ++m) {
        const int row = m * 16 + rg;
#pragma unroll
        for (int r2 = 0; r2 < 4; ++r2)
          ob[(size_t)(row + r2) * 256 + col] = acc[m][n][r2] + bvs;
      }
    }
  }
}

extern "C" void kernel_launch(void* const* d_in, const int* in_sizes, int n_in,
                              void* d_out, int out_size, void* d_ws, size_t ws_size,
                              hipStream_t stream) {
  const float* adj  = (const float*)d_in[0];
  const float* feat = (const float*)d_in[1];
  const float* w    = (const float*)d_in[2];
  const float* bias = (const float*)d_in[3];
  float* out = (float*)d_out;

  __bf16* Wt = (__bf16*)d_ws;                    // 128 KB
  __bf16* St = (__bf16*)((char*)d_ws + 131072);  // 16.78 MB

  k_wt<<<16, 256, 0, stream>>>(w, Wt);
  // gemm1: St = (feat @ W), k-subtiled output  (K=256, A ld 256)
  k_gemm<256, 256, true><<<512, 256, 0, stream>>>(feat, Wt, nullptr, nullptr, St);
  // gemm2: out = adj @ support + bias          (K=1024, A ld 1024)
  k_gemm<1024, 1024, false><<<512, 256, 0, stream>>>(adj, St, bias, out, nullptr);
}

// Round 6
// 54.086 us; speedup vs baseline: 1.3559x; 1.3559x over previous
//
#include <hip/hip_runtime.h>
#include <hip/hip_bf16.h>

// GraphConvolution: out[b] = adj[b] @ (feat[b] @ W) + bias
// B=32, N=1024, IN=256, OUT=256. fp32 in/out, bf16 MFMA internally.
//
// ws: [0,128KB)  Wt = W^T bf16, k-subtiled: [k>>3][n=256][8]
//     [128KB..)  St = support bf16, k-subtiled per batch: [b][m>>3][n=256][8]
//
// Round-6: max work per delivered byte. All rounds 1-5 hit the same
// ~10 TB/s aggregate CU-fill service ceiling; the fix is the biggest tile
// with zero redundancy: 128x256 block tile (1 block/CU, 256 blocks), BK=64,
// 8 waves (2x4, wave tile 64x64), 128 KB LDS double-buffer, staging ONLY via
// global_load_lds (async DMA). One barrier per k-step, 32 MFMA/wave/step.
//  - A staged fp32 [128][64] with 16B-chunk XOR swizzle (chunk^(row&7))
//    applied on the per-lane GLOBAL source (LDS dest linear, rule #21);
//    fp32->bf16 cvt on the read side. ds_read 2-way conflict only (free).
//  - B tiles are 32 KB contiguous in memory (k-subtiled layout) -> linear
//    DMA; LDS [8][256][8] -> 16-lane 256B-contiguous ds_read (conflict-free).

typedef __attribute__((__ext_vector_type__(4))) float  f32x4;
typedef __attribute__((__ext_vector_type__(8))) __bf16 bf16x8;
typedef __attribute__((__ext_vector_type__(4))) __bf16 bf16x4;

#define BK 64

__device__ __forceinline__ void gld16(const void* g, void* l) {
  __builtin_amdgcn_global_load_lds(
      (const __attribute__((address_space(1))) unsigned int*)g,
      (__attribute__((address_space(3))) unsigned int*)l, 16, 0, 0);
}

// ---- weight transpose: w[k][n] fp32 -> Wt k-subtiled [k>>3][n][8] bf16 -----
__global__ __launch_bounds__(256) void k_wt(const float* __restrict__ w,
                                            __bf16* __restrict__ Wt) {
  __shared__ __bf16 T[64][65];
  const int bi = blockIdx.x >> 2;  // k tile
  const int bj = blockIdx.x & 3;   // n tile
  const int t  = threadIdx.x;
  const int r  = t >> 2;
  const int q  = t & 3;
  const float* src = w + (size_t)(bi * 64 + r) * 256 + bj * 64 + q * 16;
#pragma unroll
  for (int u = 0; u < 4; ++u) {
    f32x4 v = *(const f32x4*)(src + u * 4);
    T[r][q * 16 + u * 4 + 0] = (__bf16)v[0];
    T[r][q * 16 + u * 4 + 1] = (__bf16)v[1];
    T[r][q * 16 + u * 4 + 2] = (__bf16)v[2];
    T[r][q * 16 + u * 4 + 3] = (__bf16)v[3];
  }
  __syncthreads();
  bf16x8 h0, h1;
#pragma unroll
  for (int u = 0; u < 8; ++u) {
    h0[u] = T[q * 16 + u][r];      // k = bi*64+q*16+u,   n = bj*64+r
    h1[u] = T[q * 16 + 8 + u][r];  // k = bi*64+q*16+8+u
  }
  // element (n,k) -> [(k>>3)*256 + n]*8 + (k&7)
  __bf16* d0 = Wt + ((size_t)(bi * 8 + q * 2) * 256 + (bj * 64 + r)) * 8;
  *(bf16x8*)d0          = h0;
  *(bf16x8*)(d0 + 2048) = h1;
}

// ---- main GEMM: 128x256 tile, BK=64, 512 thr (8 waves 2x4) -----------------
// EPI_ST=true : epilogue -> St k-subtiled bf16 (gemm1: feat @ W)
// EPI_ST=false: epilogue -> Out fp32 + bias, XCD swizzle (gemm2)
template <int KTOT, int LDA, bool EPI_ST>
__global__ __launch_bounds__(512, 2) void k_gemm(
    const float* __restrict__ Aall, const __bf16* __restrict__ Bg_all,
    const float* __restrict__ bias, float* __restrict__ Out,
    __bf16* __restrict__ St) {
  __shared__ float  Af[2][128 * 64];     // 32 KB each: [row][chunk-swizzled]
  __shared__ __bf16 Bf[2][8 * 256 * 8];  // 32 KB each: [chunk j][n][8]

  const int tid  = threadIdx.x;
  const int lane = tid & 63;
  const int wid  = tid >> 6;       // 0..7
  const int wr   = wid >> 2;       // 0..1 -> m offset *64
  const int wc   = wid & 3;        // 0..3 -> n offset *64
  const int l16  = lane & 15;
  const int g    = lane >> 4;      // 0..3

  int b, mblk;
  const float*  Ablk;
  const __bf16* Bblk;
  if constexpr (EPI_ST) {
    const int bx = blockIdx.x;     // 256 blocks: feat rows globally contiguous
    b    = bx >> 3;
    mblk = bx & 7;
    Ablk = Aall + (size_t)bx * 128 * LDA;
    Bblk = Bg_all;                 // Wt
  } else {
    const int h  = blockIdx.x;     // 256 % 8 == 0: bijective XCD swizzle
    const int lg = (h & 7) * 32 + (h >> 3);  // XCD x owns batches 4x..4x+3
    b    = lg >> 3;
    mblk = lg & 7;
    Ablk = Aall + (size_t)b * 1024 * 1024 + (size_t)mblk * 128 * LDA;
    Bblk = Bg_all + (size_t)b * 262144;      // St[b], k-subtiled
  }

  // --- per-thread staging sources (4 A-DMAs + 4 B-DMAs per k-step) ---
  // A: 2048 chunks of 16B; chunk c: row=c>>4, dest slot=c&15,
  //    source col-slot = (c&15)^(row&7)  (read side XORs identically)
  const float*  aS[4];
  const __bf16* bS[4];
#pragma unroll
  for (int i = 0; i < 4; ++i) {
    const int c = i * 512 + tid;
    aS[i] = Ablk + (size_t)(c >> 4) * LDA + (((c & 15) ^ ((c >> 4) & 7)) << 2);
    bS[i] = Bblk + (size_t)c * 8;
  }

#define STAGE(buf, k0)                                                        \
  {                                                                           \
    const size_t koff = (size_t)((k0) >> 3) * 2048;                           \
    _Pragma("unroll") for (int i = 0; i < 4; ++i) {                           \
      gld16(aS[i] + (k0), &Af[buf][(i * 512 + wid * 64) * 4]);                \
      gld16(bS[i] + koff, &Bf[buf][(i * 512 + wid * 64) * 8]);                \
    }                                                                         \
  }

  f32x4 acc[4][4];
#pragma unroll
  for (int m = 0; m < 4; ++m)
#pragma unroll
    for (int n = 0; n < 4; ++n) acc[m][n] = (f32x4){0.f, 0.f, 0.f, 0.f};

  auto compute = [&](int buf) {
#pragma unroll
    for (int ks = 0; ks < 2; ++ks) {
      bf16x8 af[4], bv[4];
#pragma unroll
      for (int m = 0; m < 4; ++m) {
        const int row = wr * 64 + m * 16 + l16;
        const int rx  = row & 7;
        const int c0  = (ks * 8 + 2 * g) ^ rx;
        const int c1  = (ks * 8 + 2 * g + 1) ^ rx;
        f32x4 v0 = *(const f32x4*)&Af[buf][row * 64 + c0 * 4];
        f32x4 v1 = *(const f32x4*)&Af[buf][row * 64 + c1 * 4];
        af[m] = (bf16x8){(__bf16)v0[0], (__bf16)v0[1], (__bf16)v0[2], (__bf16)v0[3],
                         (__bf16)v1[0], (__bf16)v1[1], (__bf16)v1[2], (__bf16)v1[3]};
      }
#pragma unroll
      for (int n = 0; n < 4; ++n) {
        const int col = wc * 64 + n * 16 + l16;
        bv[n] = *(const bf16x8*)&Bf[buf][((ks * 4 + g) * 256 + col) * 8];
      }
#pragma unroll
      for (int m = 0; m < 4; ++m)
#pragma unroll
        for (int n = 0; n < 4; ++n)
          acc[m][n] = __builtin_amdgcn_mfma_f32_16x16x32_bf16(af[m], bv[n], acc[m][n], 0, 0, 0);
    }
  };

  constexpr int NT = KTOT / BK;    // 16 (gemm2) or 4 (gemm1), even
  STAGE(0, 0);
  __syncthreads();                 // drains DMA -> tile 0 ready
  for (int t = 0; t < NT - 2; t += 2) {
    STAGE(1, (t + 1) * BK);        // async: in flight under compute
    compute(0);
    __syncthreads();
    STAGE(0, (t + 2) * BK);
    compute(1);
    __syncthreads();
  }
  STAGE(1, (NT - 1) * BK);
  compute(0);
  __syncthreads();
  compute(1);
#undef STAGE

  // --- epilogue. C/D frag: col = lane&15, row = (lane>>4)*4 + reg ---
  const int rg = g * 4;
  if constexpr (EPI_ST) {
    __bf16* Stb = St + (size_t)b * 262144;
    const int gm0 = mblk * 128 + wr * 64;
#pragma unroll
    for (int n = 0; n < 4; ++n) {
      const int col = wc * 64 + n * 16 + l16;
#pragma unroll
      for (int m = 0; m < 4; ++m) {
        const int gm = gm0 + m * 16 + rg;   // multiple of 4; gm&7 in {0,4}
        __bf16* dst = Stb + (size_t)(gm >> 3) * 2048 + (size_t)col * 8 + (gm & 7);
        bf16x4 hh = {(__bf16)acc[m][n][0], (__bf16)acc[m][n][1],
                     (__bf16)acc[m][n][2], (__bf16)acc[m][n][3]};
        *(bf16x4*)dst = hh;
      }
    }
  } else {
    float* ob = Out + ((size_t)b * 1024 + (size_t)mblk * 128 + wr * 64) * 256;
#pragma unroll
    for (int n = 0; n < 4; ++n) {
      const int col = wc * 64 + n * 16 + l16;
      const float bvs = bias[col];
#pragma unroll
      for (int m = 0; m < 4; ++m) {
        const int row = m * 16 + rg;
#pragma unroll
        for (int r2 = 0; r2 < 4; ++r2)
          ob[(size_t)(row + r2) * 256 + col] = acc[m][n][r2] + bvs;
      }
    }
  }
}

extern "C" void kernel_launch(void* const* d_in, const int* in_sizes, int n_in,
                              void* d_out, int out_size, void* d_ws, size_t ws_size,
                              hipStream_t stream) {
  const float* adj  = (const float*)d_in[0];
  const float* feat = (const float*)d_in[1];
  const float* w    = (const float*)d_in[2];
  const float* bias = (const float*)d_in[3];
  float* out = (float*)d_out;

  __bf16* Wt = (__bf16*)d_ws;                    // 128 KB
  __bf16* St = (__bf16*)((char*)d_ws + 131072);  // 16.78 MB

  k_wt<<<16, 256, 0, stream>>>(w, Wt);
  // gemm1: St = (feat @ W), k-subtiled output  (K=256, A ld 256)
  k_gemm<256, 256, true><<<256, 512, 0, stream>>>(feat, Wt, nullptr, nullptr, St);
  // gemm2: out = adj @ support + bias          (K=1024, A ld 1024)
  k_gemm<1024, 1024, false><<<256, 512, 0, stream>>>(adj, St, bias, out, nullptr);
}

// Round 7
// 53.067 us; speedup vs baseline: 1.3819x; 1.0192x over previous
//
#include <hip/hip_runtime.h>
#include <hip/hip_bf16.h>

// GraphConvolution: out[b] = adj[b] @ (feat[b] @ W) + bias
// B=32, N=1024, IN=256, OUT=256. fp32 in/out, bf16 MFMA internally.
//
// ws: [0,128KB)  Wt = W^T bf16, k-subtiled: [k>>3][n=256][8]
//     [128KB..)  St = support bf16, k-subtiled per batch: [b][m>>3][n=256][8]
//
// Round-7: r6 was LDS-read bound (A staged as fp32, read x4 redundantly:
// 192 KB ds_read per k-step vs ~310 cyc of MFMA). Changes:
//  - A is reg-staged: global fp32 -> regs, cvt->bf16 ONCE, swizzled
//    ds_write_b128 (slot ^= row&7 — legal now, not DMA). A LDS halves;
//    LDS reads 192->128 KB/step; cvt count /4. Write+read both spread
//    8 lanes/bank-quad = conflict-free.
//  - B stays on global_load_lds DMA (bf16 k-subtiled, linear, conflict-free),
//    issued one full compute phase before its consuming barrier.
//  - Two named A-reg sets: each load's consumer (cvt+ds_write) is a full
//    compute+barrier away -> compiler cannot sink the load to its use.
//  - T5 setprio(1) around the MFMA cluster.
// Geometry: 128x256 tile, BK=64, 8 waves (2x4, 64x64 each), LDS 96 KB.

typedef __attribute__((__ext_vector_type__(4))) float  f32x4;
typedef __attribute__((__ext_vector_type__(8))) __bf16 bf16x8;
typedef __attribute__((__ext_vector_type__(4))) __bf16 bf16x4;

#define BK 64

__device__ __forceinline__ void gld16(const void* g, void* l) {
  __builtin_amdgcn_global_load_lds(
      (const __attribute__((address_space(1))) unsigned int*)g,
      (__attribute__((address_space(3))) unsigned int*)l, 16, 0, 0);
}

// ---- weight transpose: w[k][n] fp32 -> Wt k-subtiled [k>>3][n][8] bf16 -----
__global__ __launch_bounds__(256) void k_wt(const float* __restrict__ w,
                                            __bf16* __restrict__ Wt) {
  __shared__ __bf16 T[64][65];
  const int bi = blockIdx.x >> 2;  // k tile
  const int bj = blockIdx.x & 3;   // n tile
  const int t  = threadIdx.x;
  const int r  = t >> 2;
  const int q  = t & 3;
  const float* src = w + (size_t)(bi * 64 + r) * 256 + bj * 64 + q * 16;
#pragma unroll
  for (int u = 0; u < 4; ++u) {
    f32x4 v = *(const f32x4*)(src + u * 4);
    T[r][q * 16 + u * 4 + 0] = (__bf16)v[0];
    T[r][q * 16 + u * 4 + 1] = (__bf16)v[1];
    T[r][q * 16 + u * 4 + 2] = (__bf16)v[2];
    T[r][q * 16 + u * 4 + 3] = (__bf16)v[3];
  }
  __syncthreads();
  bf16x8 h0, h1;
#pragma unroll
  for (int u = 0; u < 8; ++u) {
    h0[u] = T[q * 16 + u][r];      // k = bi*64+q*16+u,   n = bj*64+r
    h1[u] = T[q * 16 + 8 + u][r];  // k = bi*64+q*16+8+u
  }
  // element (n,k) -> [(k>>3)*256 + n]*8 + (k&7)
  __bf16* d0 = Wt + ((size_t)(bi * 8 + q * 2) * 256 + (bj * 64 + r)) * 8;
  *(bf16x8*)d0          = h0;
  *(bf16x8*)(d0 + 2048) = h1;
}

// ---- main GEMM: 128x256 tile, BK=64, 512 thr (8 waves 2x4) -----------------
// EPI_ST=true : epilogue -> St k-subtiled bf16 (gemm1: feat @ W)
// EPI_ST=false: epilogue -> Out fp32 + bias, XCD swizzle (gemm2)
template <int KTOT, int LDA, bool EPI_ST>
__global__ __launch_bounds__(512, 2) void k_gemm(
    const float* __restrict__ Aall, const __bf16* __restrict__ Bg_all,
    const float* __restrict__ bias, float* __restrict__ Out,
    __bf16* __restrict__ St) {
  __shared__ __bf16 Af[2][128 * 64];     // 16 KB each: [row][slot^(row&7)][8]
  __shared__ __bf16 Bf[2][8 * 256 * 8];  // 32 KB each: [chunk][n][8]

  const int tid  = threadIdx.x;
  const int lane = tid & 63;
  const int wid  = tid >> 6;       // 0..7
  const int wr   = wid >> 2;       // 0..1 -> m offset *64
  const int wc   = wid & 3;        // 0..3 -> n offset *64
  const int l16  = lane & 15;
  const int g    = lane >> 4;      // 0..3

  int b, mblk;
  const float*  Ablk;
  const __bf16* Bblk;
  if constexpr (EPI_ST) {
    const int bx = blockIdx.x;     // 256 blocks: feat rows globally contiguous
    b    = bx >> 3;
    mblk = bx & 7;
    Ablk = Aall + (size_t)bx * 128 * LDA;
    Bblk = Bg_all;                 // Wt
  } else {
    const int h  = blockIdx.x;     // 256 % 8 == 0: bijective XCD swizzle
    const int lg = (h & 7) * 32 + (h >> 3);  // XCD x owns batches 4x..4x+3
    b    = lg >> 3;
    mblk = lg & 7;
    Ablk = Aall + (size_t)b * 1024 * 1024 + (size_t)mblk * 128 * LDA;
    Bblk = Bg_all + (size_t)b * 262144;      // St[b], k-subtiled
  }

  // --- A staging (reg): thread t -> row=t>>2, k-cols (t&3)*16..+15 ---
  const int    srow = tid >> 2;
  const int    sq   = tid & 3;
  const float* asrc = Ablk + (size_t)srow * LDA + sq * 16;
  // swizzled LDS element offsets for the two 8-elem slots (s0=2q, s1=2q+1)
  const int wof0 = srow * 64 + (((sq * 2)     ^ (srow & 7)) << 3);
  const int wof1 = srow * 64 + (((sq * 2 + 1) ^ (srow & 7)) << 3);

  // --- B staging (DMA): thread t handles chunks {i*512+t} of 16 B ---
  const __bf16* bS[4];
#pragma unroll
  for (int i = 0; i < 4; ++i) bS[i] = Bblk + (size_t)(i * 512 + tid) * 8;

#define LOADA(S, k0)                                                          \
  {                                                                           \
    _Pragma("unroll") for (int u = 0; u < 4; ++u)                             \
        S[u] = *(const f32x4*)(asrc + (k0) + u * 4);                          \
  }
#define ISSUEB(buf, k0)                                                       \
  {                                                                           \
    const size_t koff = (size_t)((k0) >> 3) * 2048;                           \
    _Pragma("unroll") for (int i = 0; i < 4; ++i)                             \
        gld16(bS[i] + koff, &Bf[buf][(i * 512 + wid * 64) * 8]);              \
  }
#define CVTW(S, buf)                                                          \
  {                                                                           \
    bf16x8 h0 = {(__bf16)S[0][0], (__bf16)S[0][1], (__bf16)S[0][2],           \
                 (__bf16)S[0][3], (__bf16)S[1][0], (__bf16)S[1][1],           \
                 (__bf16)S[1][2], (__bf16)S[1][3]};                           \
    bf16x8 h1 = {(__bf16)S[2][0], (__bf16)S[2][1], (__bf16)S[2][2],           \
                 (__bf16)S[2][3], (__bf16)S[3][0], (__bf16)S[3][1],           \
                 (__bf16)S[3][2], (__bf16)S[3][3]};                           \
    *(bf16x8*)&Af[buf][wof0] = h0;                                            \
    *(bf16x8*)&Af[buf][wof1] = h1;                                            \
  }

  f32x4 S0[4], S1[4];

  f32x4 acc[4][4];
#pragma unroll
  for (int m = 0; m < 4; ++m)
#pragma unroll
    for (int n = 0; n < 4; ++n) acc[m][n] = (f32x4){0.f, 0.f, 0.f, 0.f};

  auto compute = [&](int buf) {
#pragma unroll
    for (int ks = 0; ks < 2; ++ks) {
      bf16x8 af[4], bv[4];
#pragma unroll
      for (int m = 0; m < 4; ++m) {
        const int row  = wr * 64 + m * 16 + l16;
        const int slot = (ks * 4 + g) ^ (row & 7);
        af[m] = *(const bf16x8*)&Af[buf][row * 64 + slot * 8];
      }
#pragma unroll
      for (int n = 0; n < 4; ++n) {
        const int col = wc * 64 + n * 16 + l16;
        bv[n] = *(const bf16x8*)&Bf[buf][((ks * 4 + g) * 256 + col) * 8];
      }
      __builtin_amdgcn_s_setprio(1);
#pragma unroll
      for (int m = 0; m < 4; ++m)
#pragma unroll
        for (int n = 0; n < 4; ++n)
          acc[m][n] = __builtin_amdgcn_mfma_f32_16x16x32_bf16(af[m], bv[n], acc[m][n], 0, 0, 0);
      __builtin_amdgcn_s_setprio(0);
    }
  };

  constexpr int NT = KTOT / BK;    // 16 (gemm2) or 4 (gemm1), even
  // prologue: tile0 -> LDS(0); tile1 regs in flight
  LOADA(S0, 0);
  ISSUEB(0, 0);
  LOADA(S1, BK);
  CVTW(S0, 0);
  __syncthreads();                 // tile 0 ready (A written, B DMA drained)

  for (int t = 0; t < NT - 2; t += 2) {   // t <= NT-4: t+2, t+3 always valid
    LOADA(S0, (t + 2) * BK);       // consumer: CVTW(S0) after next barrier
    ISSUEB(1, (t + 1) * BK);       // lands under compute(0)
    compute(0);
    CVTW(S1, 1);                   // tile t+1 -> LDS(1)
    __syncthreads();
    LOADA(S1, (t + 3) * BK);
    ISSUEB(0, (t + 2) * BK);
    compute(1);
    CVTW(S0, 0);                   // tile t+2 -> LDS(0)
    __syncthreads();
  }
  ISSUEB(1, (NT - 1) * BK);
  compute(0);                      // tile NT-2
  CVTW(S1, 1);                     // tile NT-1 -> LDS(1)
  __syncthreads();
  compute(1);                      // tile NT-1

#undef LOADA
#undef ISSUEB
#undef CVTW

  // --- epilogue. C/D frag: col = lane&15, row = (lane>>4)*4 + reg ---
  const int rg = g * 4;
  if constexpr (EPI_ST) {
    __bf16* Stb = St + (size_t)b * 262144;
    const int gm0 = mblk * 128 + wr * 64;
#pragma unroll
    for (int n = 0; n < 4; ++n) {
      const int col = wc * 64 + n * 16 + l16;
#pragma unroll
      for (int m = 0; m < 4; ++m) {
        const int gm = gm0 + m * 16 + rg;   // multiple of 4; gm&7 in {0,4}
        __bf16* dst = Stb + (size_t)(gm >> 3) * 2048 + (size_t)col * 8 + (gm & 7);
        bf16x4 hh = {(__bf16)acc[m][n][0], (__bf16)acc[m][n][1],
                     (__bf16)acc[m][n][2], (__bf16)acc[m][n][3]};
        *(bf16x4*)dst = hh;
      }
    }
  } else {
    float* ob = Out + ((size_t)b * 1024 + (size_t)mblk * 128 + wr * 64) * 256;
#pragma unroll
    for (int n = 0; n < 4; ++n) {
      const int col = wc * 64 + n * 16 + l16;
      const float bvs = bias[col];
#pragma unroll
      for (int m = 0; m < 4; ++m) {
        const int row = m * 16 + rg;
#pragma unroll
        for (int r2 = 0; r2 < 4; ++r2)
          ob[(size_t)(row + r2) * 256 + col] = acc[m][n][r2] + bvs;
      }
    }
  }
}

extern "C" void kernel_launch(void* const* d_in, const int* in_sizes, int n_in,
                              void* d_out, int out_size, void* d_ws, size_t ws_size,
                              hipStream_t stream) {
  const float* adj  = (const float*)d_in[0];
  const float* feat = (const float*)d_in[1];
  const float* w    = (const float*)d_in[2];
  const float* bias = (const float*)d_in[3];
  float* out = (float*)d_out;

  __bf16* Wt = (__bf16*)d_ws;                    // 128 KB
  __bf16* St = (__bf16*)((char*)d_ws + 131072);  // 16.78 MB

  k_wt<<<16, 256, 0, stream>>>(w, Wt);
  // gemm1: St = (feat @ W), k-subtiled output  (K=256, A ld 256)
  k_gemm<256, 256, true><<<256, 512, 0, stream>>>(feat, Wt, nullptr, nullptr, St);
  // gemm2: out = adj @ support + bias          (K=1024, A ld 1024)
  k_gemm<1024, 1024, false><<<256, 512, 0, stream>>>(adj, St, bias, out, nullptr);
}

// Round 8
// 51.557 us; speedup vs baseline: 1.4224x; 1.0293x over previous
//
#include <hip/hip_runtime.h>
#include <hip/hip_bf16.h>

// GraphConvolution: out[b] = adj[b] @ (feat[b] @ W) + bias
// B=32, N=1024, IN=256, OUT=256. fp32 in/out, bf16 MFMA internally.
//
// ws: [0,128KB)  Wt = W^T bf16, k-subtiled: [k>>3][n=256][8]
//     [128KB..)  St = support bf16, k-subtiled per batch: [b][m>>3][n=256][8]
//
// Round-8: T4 counted-vmcnt sync. r7's __syncthreads compiled to
// "s_waitcnt vmcnt(0) lgkmcnt(0); s_barrier" each k-step, draining the
// A-loads for t+2 (issued moments earlier) and the next B-DMA -> pipes
// serialize, nothing overlaps (observed dur ~= sum of pipe times).
// New scheme, ONE barrier per k-step:
//   compute(c); CVTW(A(t+1)->LDS[c^1]); LOADA(A(t+2));
//   s_waitcnt vmcnt(4) lgkmcnt(0); s_barrier;   // B(t+1) done, A(t+2) FLIES
//   ISSUEB(B(t+2)->LDS[c]); fence;              // after barrier: buf c free
// Per-thread vmem history per step = {4 A-loads, 4 B-DMAs} in fixed order,
// so vmcnt(4) exactly certifies B(t+1) (oldest 4) while A(t+2) stays in
// flight. Compiler fences after each ISSUEB stop load-hoisting (m152 trap).
// Geometry (r7-proven): 128x256 tile, BK=64, 8 waves 2x4, LDS 96 KB;
// A reg-staged fp32->bf16 with XOR slot^(row&7) swizzled ds_write_b128;
// B via global_load_lds from k-subtiled bf16 (linear, conflict-free).

typedef __attribute__((__ext_vector_type__(4))) float  f32x4;
typedef __attribute__((__ext_vector_type__(8))) __bf16 bf16x8;
typedef __attribute__((__ext_vector_type__(4))) __bf16 bf16x4;

#define BK 64

__device__ __forceinline__ void gld16(const void* g, void* l) {
  __builtin_amdgcn_global_load_lds(
      (const __attribute__((address_space(1))) unsigned int*)g,
      (__attribute__((address_space(3))) unsigned int*)l, 16, 0, 0);
}

// ---- weight transpose: w[k][n] fp32 -> Wt k-subtiled [k>>3][n][8] bf16 -----
__global__ __launch_bounds__(256) void k_wt(const float* __restrict__ w,
                                            __bf16* __restrict__ Wt) {
  __shared__ __bf16 T[64][65];
  const int bi = blockIdx.x >> 2;  // k tile
  const int bj = blockIdx.x & 3;   // n tile
  const int t  = threadIdx.x;
  const int r  = t >> 2;
  const int q  = t & 3;
  const float* src = w + (size_t)(bi * 64 + r) * 256 + bj * 64 + q * 16;
#pragma unroll
  for (int u = 0; u < 4; ++u) {
    f32x4 v = *(const f32x4*)(src + u * 4);
    T[r][q * 16 + u * 4 + 0] = (__bf16)v[0];
    T[r][q * 16 + u * 4 + 1] = (__bf16)v[1];
    T[r][q * 16 + u * 4 + 2] = (__bf16)v[2];
    T[r][q * 16 + u * 4 + 3] = (__bf16)v[3];
  }
  __syncthreads();
  bf16x8 h0, h1;
#pragma unroll
  for (int u = 0; u < 8; ++u) {
    h0[u] = T[q * 16 + u][r];      // k = bi*64+q*16+u,   n = bj*64+r
    h1[u] = T[q * 16 + 8 + u][r];  // k = bi*64+q*16+8+u
  }
  // element (n,k) -> [(k>>3)*256 + n]*8 + (k&7)
  __bf16* d0 = Wt + ((size_t)(bi * 8 + q * 2) * 256 + (bj * 64 + r)) * 8;
  *(bf16x8*)d0          = h0;
  *(bf16x8*)(d0 + 2048) = h1;
}

// ---- main GEMM: 128x256 tile, BK=64, 512 thr (8 waves 2x4) -----------------
// EPI_ST=true : epilogue -> St k-subtiled bf16 (gemm1: feat @ W)
// EPI_ST=false: epilogue -> Out fp32 + bias, XCD swizzle (gemm2)
template <int KTOT, int LDA, bool EPI_ST>
__global__ __launch_bounds__(512, 2) void k_gemm(
    const float* __restrict__ Aall, const __bf16* __restrict__ Bg_all,
    const float* __restrict__ bias, float* __restrict__ Out,
    __bf16* __restrict__ St) {
  __shared__ __bf16 Af[2][128 * 64];     // 16 KB each: [row][slot^(row&7)][8]
  __shared__ __bf16 Bf[2][8 * 256 * 8];  // 32 KB each: [chunk][n][8]

  const int tid  = threadIdx.x;
  const int lane = tid & 63;
  const int wid  = tid >> 6;       // 0..7
  const int wr   = wid >> 2;       // 0..1 -> m offset *64
  const int wc   = wid & 3;        // 0..3 -> n offset *64
  const int l16  = lane & 15;
  const int g    = lane >> 4;      // 0..3

  int b, mblk;
  const float*  Ablk;
  const __bf16* Bblk;
  if constexpr (EPI_ST) {
    const int bx = blockIdx.x;     // 256 blocks: feat rows globally contiguous
    b    = bx >> 3;
    mblk = bx & 7;
    Ablk = Aall + (size_t)bx * 128 * LDA;
    Bblk = Bg_all;                 // Wt
  } else {
    const int h  = blockIdx.x;     // 256 % 8 == 0: bijective XCD swizzle
    const int lg = (h & 7) * 32 + (h >> 3);  // XCD x owns batches 4x..4x+3
    b    = lg >> 3;
    mblk = lg & 7;
    Ablk = Aall + (size_t)b * 1024 * 1024 + (size_t)mblk * 128 * LDA;
    Bblk = Bg_all + (size_t)b * 262144;      // St[b], k-subtiled
  }

  // --- A staging (reg): thread t -> row=t>>2, k-cols (t&3)*16..+15 ---
  const int    srow = tid >> 2;
  const int    sq   = tid & 3;
  const float* asrc = Ablk + (size_t)srow * LDA + sq * 16;
  // swizzled LDS element offsets for the two 8-elem slots (s0=2q, s1=2q+1)
  const int wof0 = srow * 64 + (((sq * 2)     ^ (srow & 7)) << 3);
  const int wof1 = srow * 64 + (((sq * 2 + 1) ^ (srow & 7)) << 3);

  // --- B staging (DMA): thread t handles chunks {i*512+t} of 16 B ---
  const __bf16* bS[4];
#pragma unroll
  for (int i = 0; i < 4; ++i) bS[i] = Bblk + (size_t)(i * 512 + tid) * 8;

#define LOADA(S, k0)                                                          \
  {                                                                           \
    _Pragma("unroll") for (int u = 0; u < 4; ++u)                             \
        S[u] = *(const f32x4*)(asrc + (k0) + u * 4);                          \
  }
#define ISSUEB(buf, k0)                                                       \
  {                                                                           \
    const size_t koff = (size_t)((k0) >> 3) * 2048;                           \
    _Pragma("unroll") for (int i = 0; i < 4; ++i)                             \
        gld16(bS[i] + koff, &Bf[buf][(i * 512 + wid * 64) * 8]);              \
    asm volatile("" ::: "memory"); /* pin: later loads can't hoist above */   \
  }
#define CVTW(S, buf)                                                          \
  {                                                                           \
    bf16x8 h0 = {(__bf16)S[0][0], (__bf16)S[0][1], (__bf16)S[0][2],           \
                 (__bf16)S[0][3], (__bf16)S[1][0], (__bf16)S[1][1],           \
                 (__bf16)S[1][2], (__bf16)S[1][3]};                           \
    bf16x8 h1 = {(__bf16)S[2][0], (__bf16)S[2][1], (__bf16)S[2][2],           \
                 (__bf16)S[2][3], (__bf16)S[3][0], (__bf16)S[3][1],           \
                 (__bf16)S[3][2], (__bf16)S[3][3]};                           \
    *(bf16x8*)&Af[buf][wof0] = h0;                                            \
    *(bf16x8*)&Af[buf][wof1] = h1;                                            \
  }
// counted sync: B(t+1) (oldest 4 vmem) done; A(t+2) (newest 4) keeps flying
#define SYNC_STEP                                                             \
  asm volatile("s_waitcnt vmcnt(4) lgkmcnt(0)\n\ts_barrier" ::: "memory")
#define SYNC_LAST                                                             \
  asm volatile("s_waitcnt vmcnt(0) lgkmcnt(0)\n\ts_barrier" ::: "memory")

  f32x4 S0[4], S1[4];

  f32x4 acc[4][4];
#pragma unroll
  for (int m = 0; m < 4; ++m)
#pragma unroll
    for (int n = 0; n < 4; ++n) acc[m][n] = (f32x4){0.f, 0.f, 0.f, 0.f};

  auto compute = [&](int buf) {
#pragma unroll
    for (int ks = 0; ks < 2; ++ks) {
      bf16x8 af[4], bv[4];
#pragma unroll
      for (int m = 0; m < 4; ++m) {
        const int row  = wr * 64 + m * 16 + l16;
        const int slot = (ks * 4 + g) ^ (row & 7);
        af[m] = *(const bf16x8*)&Af[buf][row * 64 + slot * 8];
      }
#pragma unroll
      for (int n = 0; n < 4; ++n) {
        const int col = wc * 64 + n * 16 + l16;
        bv[n] = *(const bf16x8*)&Bf[buf][((ks * 4 + g) * 256 + col) * 8];
      }
      __builtin_amdgcn_s_setprio(1);
#pragma unroll
      for (int m = 0; m < 4; ++m)
#pragma unroll
        for (int n = 0; n < 4; ++n)
          acc[m][n] = __builtin_amdgcn_mfma_f32_16x16x32_bf16(af[m], bv[n], acc[m][n], 0, 0, 0);
      __builtin_amdgcn_s_setprio(0);
    }
  };

  constexpr int NT = KTOT / BK;    // 16 (gemm2) or 4 (gemm1), even
  // prologue: A(t0)->LDS0, B(t0) DMA, A(t1)->regs; counted sync; B(t1) DMA
  LOADA(S0, 0);
  ISSUEB(0, 0);
  CVTW(S0, 0);                     // compiler waits A(t0) regs, ds_writes
  LOADA(S1, BK);
  SYNC_STEP;                       // B(t0) arrived; A(t1) still flying
  ISSUEB(1, BK);

  for (int t = 0; t < NT - 2; t += 2) {
    compute(0);                    // tile t
    CVTW(S1, 1);                   // A(t+1) -> LDS[1]
    LOADA(S0, (t + 2) * BK);       // A(t+2) -> regs (flies through sync)
    SYNC_STEP;                     // B(t+1) arrived -> tile t+1 ready
    ISSUEB(0, (t + 2) * BK);       // buf0 free now (everyone done reading)

    compute(1);                    // tile t+1
    CVTW(S0, 0);                   // A(t+2) -> LDS[0]
    LOADA(S1, (t + 3) * BK);       // A(t+3)
    SYNC_STEP;                     // B(t+2) arrived
    ISSUEB(1, (t + 3) * BK);
  }
  compute(0);                      // tile NT-2
  CVTW(S1, 1);                     // A(NT-1) -> LDS[1]
  SYNC_LAST;                       // drain B(NT-1)
  compute(1);                      // tile NT-1

#undef LOADA
#undef ISSUEB
#undef CVTW
#undef SYNC_STEP
#undef SYNC_LAST

  // --- epilogue. C/D frag: col = lane&15, row = (lane>>4)*4 + reg ---
  const int rg = g * 4;
  if constexpr (EPI_ST) {
    __bf16* Stb = St + (size_t)b * 262144;
    const int gm0 = mblk * 128 + wr * 64;
#pragma unroll
    for (int n = 0; n < 4; ++n) {
      const int col = wc * 64 + n * 16 + l16;
#pragma unroll
      for (int m = 0; m < 4; ++m) {
        const int gm = gm0 + m * 16 + rg;   // multiple of 4; gm&7 in {0,4}
        __bf16* dst = Stb + (size_t)(gm >> 3) * 2048 + (size_t)col * 8 + (gm & 7);
        bf16x4 hh = {(__bf16)acc[m][n][0], (__bf16)acc[m][n][1],
                     (__bf16)acc[m][n][2], (__bf16)acc[m][n][3]};
        *(bf16x4*)dst = hh;
      }
    }
  } else {
    float* ob = Out + ((size_t)b * 1024 + (size_t)mblk * 128 + wr * 64) * 256;
#pragma unroll
    for (int n = 0; n < 4; ++n) {
      const int col = wc * 64 + n * 16 + l16;
      const float bvs = bias[col];
#pragma unroll
      for (int m = 0; m < 4; ++m) {
        const int row = m * 16 + rg;
#pragma unroll
        for (int r2 = 0; r2 < 4; ++r2)
          ob[(size_t)(row + r2) * 256 + col] = acc[m][n][r2] + bvs;
      }
    }
  }
}

extern "C" void kernel_launch(void* const* d_in, const int* in_sizes, int n_in,
                              void* d_out, int out_size, void* d_ws, size_t ws_size,
                              hipStream_t stream) {
  const float* adj  = (const float*)d_in[0];
  const float* feat = (const float*)d_in[1];
  const float* w    = (const float*)d_in[2];
  const float* bias = (const float*)d_in[3];
  float* out = (float*)d_out;

  __bf16* Wt = (__bf16*)d_ws;                    // 128 KB
  __bf16* St = (__bf16*)((char*)d_ws + 131072);  // 16.78 MB

  k_wt<<<16, 256, 0, stream>>>(w, Wt);
  // gemm1: St = (feat @ W), k-subtiled output  (K=256, A ld 256)
  k_gemm<256, 256, true><<<256, 512, 0, stream>>>(feat, Wt, nullptr, nullptr, St);
  // gemm2: out = adj @ support + bias          (K=1024, A ld 1024)
  k_gemm<1024, 1024, false><<<256, 512, 0, stream>>>(adj, St, bias, out, nullptr);
}